// Round 3
// baseline (417.653 us; speedup 1.0000x reference)
//
#include <hip/hip_runtime.h>
#include <hip/hip_bf16.h>

// Problem constants (BayesianLinear): IN_F=64, OUT_F=32, N=2080, B*S=16384
#define IN_F  64
#define OUT_F 32
#define NV    2080           // N
#define NPAD  2176           // 17*128
#define MM    16384          // tokens
#define KK    2080           // contraction dim
#define NTC   8              // K-chunks: t strided by 8 -> 8 y-partial slabs
#define BM    256            // row-tile

typedef __attribute__((ext_vector_type(4))) float f32x4;
typedef __bf16 bf16x8 __attribute__((ext_vector_type(8)));

using gas_ptr = const __attribute__((address_space(1))) void*;
using lds_ptr = __attribute__((address_space(3))) void*;

// ---------------------------------------------------------------------------
// Kernel 1: build L (bf16, row-major [NPAD][KK]); rows >= NV are zero.
// ---------------------------------------------------------------------------
__global__ __launch_bounds__(256) void build_L_k(const float* __restrict__ cov,
                                                 const float* __restrict__ logvar,
                                                 __hip_bfloat16* __restrict__ LB) {
    const int idx = blockIdx.x * 256 + threadIdx.x;   // over NPAD*KK
    const int m = idx / KK;
    const int k = idx - m * KK;
    float v = 0.0f;
    if (m < NV) {
        if (k < m)       v = cov[(size_t)(m * (m - 1) / 2) + k];
        else if (k == m) v = expf(0.5f * logvar[m]);
    }
    LB[idx] = __float2bfloat16(v);
}

// ---------------------------------------------------------------------------
// Kernel 2 (v4): fused GEMM with PER-STEP x-contraction.
// y[s,k] = sum_t sum_c w[s,c] * (eps(t-slice) . L^T(t-slice))  -- linearity
// lets us contract each K-step's partial Z immediately, so:
//   * no persistent Z accumulator (MFMA C-in = 0, result -> 4 VALU FMA/tile
//     into a 32-float/lane y-accumulator)
//   * loop t-OUTER / bn-INNER: A(t) (eps, fp32->bf16 reg-cvt) staged into LDS
//     and read to af[] registers ONCE per t, reused across all active bn
//     (bn >= t>>2).  eps is read from HBM ONCE (was x17).
//   * per-step LDS = 8 B-frag ds_read_b128 per wave only (was 16 incl. A).
// Output orientation via SWAPPED mfma operands: mfma(bfr, af, 0) -> D reg r
// on lane (q,r16) = Z[eps_row = 64*wave+16i+r16][Lcol = 128bn+16j+4q+r].
// Column algebra: col-32 = 32*(4bn+c-1) + 16d+4q+r with c=j>>1, d=j&1
//   => h = 4bn+c-1, k = 16d+4q+r; bias = (bn==0,c==0) w=1.
// loc folded in at t==0 steps (tc==0 blocks see every bn exactly once there).
// K strided: block (bm, tc) handles t = tc, tc+8, ..., <=64  (72..81 steps).
// B (L) double-buffered glds, counted vmcnt keeps next-step w-loads in
// flight across the raw s_barrier.  w (x-weights) prefetched distance-1
// from global (L2-hot, 4 dwordx4/lane).
// ---------------------------------------------------------------------------
__global__ __launch_bounds__(256) void gemm_v4_k(const float* __restrict__ A,
                                                 const __hip_bfloat16* __restrict__ BT,
                                                 const float* __restrict__ loc,
                                                 const float* __restrict__ x,
                                                 float* __restrict__ Ypart) {
    __shared__ __align__(16) __hip_bfloat16 As[2][BM * 32];    // 32 KB (per-t dbuf)
    __shared__ __align__(16) __hip_bfloat16 Bs[2][128 * 32];   // 16 KB (per-step dbuf)

    const int tid  = threadIdx.x;
    const int bm   = blockIdx.x;   // 0..63
    const int tc   = blockIdx.y;   // 0..7
    const int wave = tid >> 6;
    const int lane = tid & 63;
    const int quad = lane >> 4;
    const int r16  = lane & 15;

    const float* __restrict__ Ag = A + (size_t)bm * BM * KK;

    // A staging map (verified): 1024 chunks of 8 elems, 4/thread; chunk c ->
    // LDS slot (row=c>>2, q=c&3) holding global part p=(c&3)^((row>>1)&3).
    size_t agofs[4]; int aldso[4];
#pragma unroll
    for (int u = 0; u < 4; u++) {
        const int c = tid + 256 * u;
        const int r = c >> 2, p = (c & 3) ^ ((r >> 1) & 3);
        agofs[u] = (size_t)r * KK + (size_t)(p * 8);
        aldso[u] = c * 8;
    }
    // B staging map: 512 chunks, 2/thread, same swizzle (glds path).
    size_t bgofs[2]; int bldso[2];
#pragma unroll
    for (int u = 0; u < 2; u++) {
        const int c = tid + 256 * u;
        const int r = c >> 2, p = (c & 3) ^ ((r >> 1) & 3);
        bgofs[u] = (size_t)r * KK + (size_t)(p * 8);
        bldso[u] = c * 8;
    }

    // fragment-read LDS offsets (elements), verified swizzle
    int aofs[4], bofs[8];
#pragma unroll
    for (int i = 0; i < 4; i++) {
        const int arow = 64 * wave + 16 * i + r16;
        aofs[i] = arow * 32 + (quad ^ ((arow >> 1) & 3)) * 8;
    }
#pragma unroll
    for (int j = 0; j < 8; j++) {
        const int brow = 16 * j + r16;
        bofs[j] = brow * 32 + (quad ^ ((brow >> 1) & 3)) * 8;
    }

    // per-lane eps rows (y rows): row_i = 64*wave + 16i + r16
    int rowi[4];
#pragma unroll
    for (int i = 0; i < 4; i++) rowi[i] = bm * BM + 64 * wave + 16 * i + r16;

    f32x4 yacc[4][2];   // [i][d], vector over r: y[row_i][16d+4q+r]
#pragma unroll
    for (int i = 0; i < 4; i++) { yacc[i][0] = f32x4{0.f,0.f,0.f,0.f}; yacc[i][1] = f32x4{0.f,0.f,0.f,0.f}; }

    f32x4 ra[8];   // in-flight A K-tile (fp32), statically indexed

    auto loadA = [&](int t) __attribute__((always_inline)) {
        const size_t k0 = (size_t)t * 32;
#pragma unroll
        for (int u = 0; u < 4; u++) {
            ra[2 * u]     = *(const f32x4*)(Ag + k0 + agofs[u]);
            ra[2 * u + 1] = *(const f32x4*)(Ag + k0 + agofs[u] + 4);
        }
    };
    auto writeA = [&](int buf) __attribute__((always_inline)) {
#pragma unroll
        for (int u = 0; u < 4; u++) {
            bf16x8 w;
#pragma unroll
            for (int q = 0; q < 4; q++) {
                w[q]     = (__bf16)ra[2 * u][q];
                w[4 + q] = (__bf16)ra[2 * u + 1][q];
            }
            *(bf16x8*)(&As[buf][0] + aldso[u]) = w;
        }
    };
    auto stageB = [&](int t, int bn, int buf) __attribute__((always_inline)) {
        const __hip_bfloat16* Bg = BT + (size_t)bn * 128 * KK + (size_t)t * 32;
#pragma unroll
        for (int u = 0; u < 2; u++)
            __builtin_amdgcn_global_load_lds((gas_ptr)(Bg + bgofs[u]),
                                             (lds_ptr)(&Bs[buf][0] + bldso[u]), 16, 0, 0);
    };
    auto loadW = [&](int bn, f32x4* w) __attribute__((always_inline)) {
        // w[i][c] = weight for h=4bn-1+c at row_i; bias (1) at bn==0,c==0
        if (bn == 0) {
#pragma unroll
            for (int i = 0; i < 4; i++) {
                f32x4 v = *(const f32x4*)(x + (size_t)rowi[i] * IN_F);
                w[i] = f32x4{1.0f, v[0], v[1], v[2]};
            }
        } else if (bn == 16) {
#pragma unroll
            for (int i = 0; i < 4; i++) {
                float v = x[(size_t)rowi[i] * IN_F + 63];
                w[i] = f32x4{v, 0.f, 0.f, 0.f};
            }
        } else {
#pragma unroll
            for (int i = 0; i < 4; i++)
                w[i] = *(const f32x4*)(x + (size_t)rowi[i] * IN_F + 4 * bn - 1);
        }
    };

    // --- prologue: first step (t=tc, bn=tc>>2) ---
    int t = tc, bn = tc >> 2;
    loadA(t);
    stageB(t, bn, 0);
    f32x4 w[4];
    loadW(bn, w);
    writeA(0);                                         // compiler waits ra
    asm volatile("s_waitcnt vmcnt(0)" ::: "memory");
    asm volatile("s_waitcnt lgkmcnt(0)" ::: "memory");
    __builtin_amdgcn_s_barrier();
    __builtin_amdgcn_sched_barrier(0);

    bf16x8 af[4];
#pragma unroll
    for (int i = 0; i < 4; i++) af[i] = *(const bf16x8*)(&As[0][0] + aofs[i]);
    int abuf = 0, bbuf = 0;

    for (;;) {
        // next step in the (t strided by 8, bn ascending) sequence
        int t1, bn1; bool hasNext;
        if (bn < 16) { t1 = t; bn1 = bn + 1; hasNext = true; }
        else         { t1 = t + NTC; bn1 = t1 >> 2; hasNext = (t1 <= KK / 32 - 1); }
        const bool stA = (bn == 16) && hasNext;

        if (hasNext) stageB(t1, bn1, bbuf ^ 1);   // oldest vm ops this step
        f32x4 wn[4];
        if (hasNext) loadW(bn1, wn);              // next 4 vm ops
        if (stA) loadA(t1);                       // newest (8) on boundary steps

        const bool addloc = (t == 0);             // t==0 only exists in tc==0
        f32x4 lv[8];
        if (addloc) {
#pragma unroll
            for (int j = 0; j < 8; j++) {
                const int cb = 128 * bn + 16 * j + 4 * quad;
                lv[j] = (cb < NV - 3) ? *(const f32x4*)(loc + cb) : f32x4{0.f,0.f,0.f,0.f};
            }
        }

        const int jlo = (2 * t > 8 * bn) ? (2 * t - 8 * bn) : 0;   // triangular frag-skip
        const __hip_bfloat16* bs = &Bs[bbuf][0];
        __builtin_amdgcn_s_setprio(1);
#pragma unroll
        for (int j = 0; j < 8; j++) {
            if (j >= jlo) {
                const bf16x8 bfr = *(const bf16x8*)(bs + bofs[j]);
#pragma unroll
                for (int i = 0; i < 4; i++) {
                    // SWAPPED operands: D[Lcol=16j+4q+r][eps_row=16i+r16]
                    f32x4 tl = __builtin_amdgcn_mfma_f32_16x16x32_bf16(
                                   bfr, af[i], f32x4{0.f,0.f,0.f,0.f}, 0, 0, 0);
                    if (addloc) tl += lv[j];
                    const float wc = w[i][j >> 1];
                    yacc[i][j & 1] += wc * tl;
                }
            }
        }
        __builtin_amdgcn_s_setprio(0);

        if (!hasNext) break;

        if (stA) {
            asm volatile("s_waitcnt vmcnt(0)" ::: "memory");   // A(t1) raw landed (B,wn too)
            writeA(abuf ^ 1);
        } else {
            // outstanding oldest->newest: B(next)[2], wn[4] (lv already consumed)
            asm volatile("s_waitcnt vmcnt(4)" ::: "memory");   // B landed; keep wn in flight
        }
        asm volatile("s_waitcnt lgkmcnt(0)" ::: "memory");
        __builtin_amdgcn_s_barrier();
        __builtin_amdgcn_sched_barrier(0);

        if (stA) {
            abuf ^= 1;
#pragma unroll
            for (int i = 0; i < 4; i++) af[i] = *(const bf16x8*)(&As[abuf][0] + aofs[i]);
        }
        bbuf ^= 1;
#pragma unroll
        for (int i = 0; i < 4; i++) w[i] = wn[i];
        t = t1; bn = bn1;
    }

    // --- epilogue: store y-partial slab tc ---
    float* yp = Ypart + ((size_t)tc * MM + (size_t)bm * BM) * OUT_F;
#pragma unroll
    for (int i = 0; i < 4; i++) {
        const int row = 64 * wave + 16 * i + r16;
#pragma unroll
        for (int d = 0; d < 2; d++)
            *(f32x4*)(yp + (size_t)row * OUT_F + 16 * d + 4 * quad) = yacc[i][d];
    }
}

// ---------------------------------------------------------------------------
// Kernel 3: reduce 8 partials -> y
// ---------------------------------------------------------------------------
__global__ __launch_bounds__(256) void reduce8_k(const float4* __restrict__ yp,
                                                 float4* __restrict__ y) {
    const size_t i = (size_t)blockIdx.x * 256 + threadIdx.x;   // MM*32/4
    float4 s = yp[i];
#pragma unroll
    for (int b = 1; b < NTC; b++) {
        float4 v = yp[i + (size_t)b * (MM * OUT_F / 4)];
        s.x += v.x; s.y += v.y; s.z += v.z; s.w += v.w;
    }
    y[i] = s;
}

// ---------------------------------------------------------------------------
extern "C" void kernel_launch(void* const* d_in, const int* in_sizes, int n_in,
                              void* d_out, int out_size, void* d_ws, size_t ws_size,
                              hipStream_t stream) {
    const float* x      = (const float*)d_in[0];
    const float* eps    = (const float*)d_in[1];
    const float* loc    = (const float*)d_in[2];
    const float* logvar = (const float*)d_in[3];
    const float* cov    = (const float*)d_in[4];
    float* y = (float*)d_out;

    char* ws = (char*)d_ws;
    const size_t lb_bytes = (size_t)NPAD * KK * 2;            //  9.05 MB
    __hip_bfloat16* LB    = (__hip_bfloat16*)ws;
    float*          Ypart = (float*)(ws + lb_bytes);          // 8*MM*32*4 = 16.8 MB

    build_L_k<<<(NPAD * KK) / 256, 256, 0, stream>>>(cov, logvar, LB);
    gemm_v4_k<<<dim3(MM / BM, NTC), 256, 0, stream>>>(eps, LB, loc, x, Ypart);
    reduce8_k<<<(MM * OUT_F / 4) / 256, 256, 0, stream>>>((const float4*)Ypart, (float4*)y);
}